// Round 1
// baseline (513.294 us; speedup 1.0000x reference)
//
#include <hip/hip_runtime.h>

// Problem constants (from reference setup_inputs)
constexpr int N_POINTS = 2000000;
constexpr int C = 32;          // DIM_FEAT
constexpr int H = 1024;        // GRID_H
constexpr int W = 1024;        // GRID_W

// ---------------------------------------------------------------------------
// Kernel 1: transpose params [C][H][W] -> [H][W][C] (channel-last) so that the
// 32 channels of one texel are 128 B contiguous. LDS-tiled so both the global
// load (64 consecutive x per channel) and the global store (32 consecutive
// channels, adjacent x blocks contiguous) are fully coalesced.
// Grid: (W/64, H), block 256.
// ---------------------------------------------------------------------------
__global__ __launch_bounds__(256) void transpose_chw_hwc(
    const float* __restrict__ in, float* __restrict__ out)
{
    __shared__ float tile[64][C + 1];   // +1 pad: stride 33 -> conflict-free
    const int x0  = blockIdx.x * 64;
    const int y   = blockIdx.y;
    const int tid = threadIdx.x;

    // Load: tid%64 = x offset (coalesced 256B per channel row), tid/64 = channel lane.
    const int li = tid & 63;
    const int lc = tid >> 6;            // 0..3
#pragma unroll
    for (int r = 0; r < 8; ++r) {
        const int c = r * 4 + lc;
        tile[li][c] = in[(size_t)c * (H * W) + (size_t)y * W + x0 + li];
    }
    __syncthreads();

    // Store: tid%32 = channel (contiguous 128B), tid/32 = x sub-offset.
    // A wave covers 2 adjacent x -> 256B contiguous store.
    const int wc  = tid & 31;
    const int wi0 = tid >> 5;           // 0..7
#pragma unroll
    for (int r = 0; r < 8; ++r) {
        const int i = r * 8 + wi0;
        out[((size_t)y * W + x0 + i) * C + wc] = tile[i][wc];
    }
}

// ---------------------------------------------------------------------------
// Kernel 2: bilinear sample from channel-last grid.
// 8 lanes per point; lane j handles channels [4j, 4j+4) via float4 loads.
// Each corner read = 128 B contiguous per point; output store coalesced.
// ---------------------------------------------------------------------------
__global__ __launch_bounds__(256) void sample_hwc(
    const float* __restrict__ coord, const float* __restrict__ tp,
    float* __restrict__ out)
{
    const int tid = blockIdx.x * blockDim.x + threadIdx.x;
    const int n = tid >> 3;             // point index
    const int j = tid & 7;              // float4 slot within the 32 channels
    if (n >= N_POINTS) return;

    const float2 xy = ((const float2*)coord)[n];

    // Match reference: ix = (x+1)*0.5*(W-1), align_corners=True
    const float ix = (xy.x + 1.0f) * 0.5f * (float)(W - 1);
    const float iy = (xy.y + 1.0f) * 0.5f * (float)(H - 1);
    const float ix0f = floorf(ix), iy0f = floorf(iy);
    const float ix1f = ix0f + 1.0f, iy1f = iy0f + 1.0f;

    const float w_nw = (ix1f - ix) * (iy1f - iy);
    const float w_ne = (ix - ix0f) * (iy1f - iy);
    const float w_sw = (ix1f - ix) * (iy - iy0f);
    const float w_se = (ix - ix0f) * (iy - iy0f);

    const int x0 = (int)fminf(fmaxf(ix0f, 0.0f), (float)(W - 1));
    const int x1 = (int)fminf(fmaxf(ix1f, 0.0f), (float)(W - 1));
    const int y0 = (int)fminf(fmaxf(iy0f, 0.0f), (float)(H - 1));
    const int y1 = (int)fminf(fmaxf(iy1f, 0.0f), (float)(H - 1));

    const int off = j * 4;
    const float4 vnw = *(const float4*)&tp[((size_t)(y0 * W + x0)) * C + off];
    const float4 vne = *(const float4*)&tp[((size_t)(y0 * W + x1)) * C + off];
    const float4 vsw = *(const float4*)&tp[((size_t)(y1 * W + x0)) * C + off];
    const float4 vse = *(const float4*)&tp[((size_t)(y1 * W + x1)) * C + off];

    float4 r;
    r.x = vnw.x * w_nw + vne.x * w_ne + vsw.x * w_sw + vse.x * w_se;
    r.y = vnw.y * w_nw + vne.y * w_ne + vsw.y * w_sw + vse.y * w_se;
    r.z = vnw.z * w_nw + vne.z * w_ne + vsw.z * w_sw + vse.z * w_se;
    r.w = vnw.w * w_nw + vne.w * w_ne + vsw.w * w_sw + vse.w * w_se;

    *(float4*)&out[(size_t)n * C + off] = r;
}

// ---------------------------------------------------------------------------
// Fallback (only if ws_size < 128 MiB): gather directly from channel-major
// params. 32 lanes per point, lane = channel, scalar loads. Slow but correct.
// ---------------------------------------------------------------------------
__global__ __launch_bounds__(256) void sample_chw(
    const float* __restrict__ coord, const float* __restrict__ p,
    float* __restrict__ out)
{
    const int tid = blockIdx.x * blockDim.x + threadIdx.x;
    const int n = tid >> 5;
    const int c = tid & 31;
    if (n >= N_POINTS) return;

    const float2 xy = ((const float2*)coord)[n];
    const float ix = (xy.x + 1.0f) * 0.5f * (float)(W - 1);
    const float iy = (xy.y + 1.0f) * 0.5f * (float)(H - 1);
    const float ix0f = floorf(ix), iy0f = floorf(iy);
    const float ix1f = ix0f + 1.0f, iy1f = iy0f + 1.0f;

    const float w_nw = (ix1f - ix) * (iy1f - iy);
    const float w_ne = (ix - ix0f) * (iy1f - iy);
    const float w_sw = (ix1f - ix) * (iy - iy0f);
    const float w_se = (ix - ix0f) * (iy - iy0f);

    const int x0 = (int)fminf(fmaxf(ix0f, 0.0f), (float)(W - 1));
    const int x1 = (int)fminf(fmaxf(ix1f, 0.0f), (float)(W - 1));
    const int y0 = (int)fminf(fmaxf(iy0f, 0.0f), (float)(H - 1));
    const int y1 = (int)fminf(fmaxf(iy1f, 0.0f), (float)(H - 1));

    const size_t plane = (size_t)c * (H * W);
    const float vnw = p[plane + (size_t)y0 * W + x0];
    const float vne = p[plane + (size_t)y0 * W + x1];
    const float vsw = p[plane + (size_t)y1 * W + x0];
    const float vse = p[plane + (size_t)y1 * W + x1];

    out[(size_t)n * C + c] = vnw * w_nw + vne * w_ne + vsw * w_sw + vse * w_se;
}

extern "C" void kernel_launch(void* const* d_in, const int* in_sizes, int n_in,
                              void* d_out, int out_size, void* d_ws, size_t ws_size,
                              hipStream_t stream)
{
    const float* coord  = (const float*)d_in[0];   // [N, 2]
    const float* params = (const float*)d_in[1];   // [1, C, H, W]
    float* out = (float*)d_out;                    // [N, C]

    const size_t needed = (size_t)C * H * W * sizeof(float);   // 128 MiB

    if (ws_size >= needed) {
        float* tp = (float*)d_ws;   // [H, W, C]
        dim3 tgrid(W / 64, H);
        transpose_chw_hwc<<<tgrid, 256, 0, stream>>>(params, tp);

        const int total = N_POINTS * 8;            // 8 lanes per point
        const int blocks = (total + 255) / 256;
        sample_hwc<<<blocks, 256, 0, stream>>>(coord, tp, out);
    } else {
        const int total = N_POINTS * 32;           // 32 lanes per point
        const int blocks = (total + 255) / 256;
        sample_chw<<<blocks, 256, 0, stream>>>(coord, params, out);
    }
}

// Round 3
// 491.039 us; speedup vs baseline: 1.0453x; 1.0453x over previous
//
#include <hip/hip_runtime.h>

// Problem constants (from reference setup_inputs)
constexpr int N_POINTS = 2000000;
constexpr int C = 32;          // DIM_FEAT
constexpr int H = 1024;        // GRID_H
constexpr int W = 1024;        // GRID_W

// Native clang vector types — required by __builtin_nontemporal_* (the HIP
// wrapper classes float4/float2 are rejected by the builtin).
typedef float f32x4 __attribute__((ext_vector_type(4)));
typedef float f32x2 __attribute__((ext_vector_type(2)));

// ---------------------------------------------------------------------------
// Kernel 1: transpose params [C][H][W] -> [H][W][C] (channel-last), so the 32
// channels of one texel are one 128 B cache line. float4 on both global sides.
// params is read once -> non-temporal loads (keep L3 for the tp array, which
// the sampler will hammer). tp stores stay cached.
// Grid: (W/64, H), block 256.
// ---------------------------------------------------------------------------
__global__ __launch_bounds__(256) void transpose_chw_hwc(
    const float* __restrict__ in, float* __restrict__ out)
{
    __shared__ float tile[64][C + 1];   // stride 33: <=2-way bank alias (free)
    const int x0  = blockIdx.x * 64;
    const int y   = blockIdx.y;
    const int tid = threadIdx.x;

    // Load: 512 float4 per tile, 2 per thread. Per wave: 4 channel rows ×
    // 256 B contiguous each. Non-temporal (single use).
#pragma unroll
    for (int r = 0; r < 2; ++r) {
        const int idx = tid + 256 * r;      // 0..511
        const int c   = idx >> 4;           // 0..31
        const int xq  = idx & 15;           // 0..15
        const f32x4 v = __builtin_nontemporal_load(
            (const f32x4*)&in[(size_t)c * (H * W) + (size_t)y * W + x0 + xq * 4]);
        tile[xq * 4 + 0][c] = v.x;
        tile[xq * 4 + 1][c] = v.y;
        tile[xq * 4 + 2][c] = v.z;
        tile[xq * 4 + 3][c] = v.w;
    }
    __syncthreads();

    // Store: the tile's output range is one contiguous 8 KB block.
#pragma unroll
    for (int r = 0; r < 2; ++r) {
        const int idx = tid + 256 * r;      // 0..511
        const int x   = idx >> 3;           // 0..63
        const int c4  = idx & 7;            // 0..7
        f32x4 v;
        v.x = tile[x][c4 * 4 + 0];
        v.y = tile[x][c4 * 4 + 1];
        v.z = tile[x][c4 * 4 + 2];
        v.w = tile[x][c4 * 4 + 3];
        *(f32x4*)&out[((size_t)y * W + x0 + x) * C + c4 * 4] = v;
    }
}

// ---------------------------------------------------------------------------
// Kernel 2: bilinear sample from channel-last grid.
// 8 lanes per point; lane j handles channels [4j, 4j+4) via float4 loads.
// Output stores + coord loads are NON-TEMPORAL so the 256 MB write stream and
// 16 MB coord stream don't evict the L3-resident 128 MiB grid.
// ---------------------------------------------------------------------------
__global__ __launch_bounds__(256) void sample_hwc(
    const float* __restrict__ coord, const float* __restrict__ tp,
    float* __restrict__ out)
{
    const int tid = blockIdx.x * blockDim.x + threadIdx.x;
    const int n = tid >> 3;             // point index
    const int j = tid & 7;              // float4 slot within the 32 channels
    if (n >= N_POINTS) return;

    const f32x2 xy = __builtin_nontemporal_load(&((const f32x2*)coord)[n]);

    // Match reference: ix = (x+1)*0.5*(W-1), align_corners=True
    const float ix = (xy.x + 1.0f) * 0.5f * (float)(W - 1);
    const float iy = (xy.y + 1.0f) * 0.5f * (float)(H - 1);
    const float ix0f = floorf(ix), iy0f = floorf(iy);
    const float ix1f = ix0f + 1.0f, iy1f = iy0f + 1.0f;

    const float w_nw = (ix1f - ix) * (iy1f - iy);
    const float w_ne = (ix - ix0f) * (iy1f - iy);
    const float w_sw = (ix1f - ix) * (iy - iy0f);
    const float w_se = (ix - ix0f) * (iy - iy0f);

    const int x0 = (int)fminf(fmaxf(ix0f, 0.0f), (float)(W - 1));
    const int x1 = (int)fminf(fmaxf(ix1f, 0.0f), (float)(W - 1));
    const int y0 = (int)fminf(fmaxf(iy0f, 0.0f), (float)(H - 1));
    const int y1 = (int)fminf(fmaxf(iy1f, 0.0f), (float)(H - 1));

    const int off = j * 4;
    const f32x4 vnw = *(const f32x4*)&tp[((size_t)(y0 * W + x0)) * C + off];
    const f32x4 vne = *(const f32x4*)&tp[((size_t)(y0 * W + x1)) * C + off];
    const f32x4 vsw = *(const f32x4*)&tp[((size_t)(y1 * W + x0)) * C + off];
    const f32x4 vse = *(const f32x4*)&tp[((size_t)(y1 * W + x1)) * C + off];

    f32x4 r = vnw * w_nw + vne * w_ne + vsw * w_sw + vse * w_se;

    __builtin_nontemporal_store(r, (f32x4*)&out[(size_t)n * C + off]);
}

// ---------------------------------------------------------------------------
// Fallback (only if ws_size < 128 MiB): gather directly from channel-major
// params. 32 lanes per point, lane = channel, scalar loads. Slow but correct.
// ---------------------------------------------------------------------------
__global__ __launch_bounds__(256) void sample_chw(
    const float* __restrict__ coord, const float* __restrict__ p,
    float* __restrict__ out)
{
    const int tid = blockIdx.x * blockDim.x + threadIdx.x;
    const int n = tid >> 5;
    const int c = tid & 31;
    if (n >= N_POINTS) return;

    const float2 xy = ((const float2*)coord)[n];
    const float ix = (xy.x + 1.0f) * 0.5f * (float)(W - 1);
    const float iy = (xy.y + 1.0f) * 0.5f * (float)(H - 1);
    const float ix0f = floorf(ix), iy0f = floorf(iy);
    const float ix1f = ix0f + 1.0f, iy1f = iy0f + 1.0f;

    const float w_nw = (ix1f - ix) * (iy1f - iy);
    const float w_ne = (ix - ix0f) * (iy1f - iy);
    const float w_sw = (ix1f - ix) * (iy - iy0f);
    const float w_se = (ix - ix0f) * (iy - iy0f);

    const int x0 = (int)fminf(fmaxf(ix0f, 0.0f), (float)(W - 1));
    const int x1 = (int)fminf(fmaxf(ix1f, 0.0f), (float)(W - 1));
    const int y0 = (int)fminf(fmaxf(iy0f, 0.0f), (float)(H - 1));
    const int y1 = (int)fminf(fmaxf(iy1f, 0.0f), (float)(H - 1));

    const size_t plane = (size_t)c * (H * W);
    const float vnw = p[plane + (size_t)y0 * W + x0];
    const float vne = p[plane + (size_t)y0 * W + x1];
    const float vsw = p[plane + (size_t)y1 * W + x0];
    const float vse = p[plane + (size_t)y1 * W + x1];

    out[(size_t)n * C + c] = vnw * w_nw + vne * w_ne + vsw * w_sw + vse * w_se;
}

extern "C" void kernel_launch(void* const* d_in, const int* in_sizes, int n_in,
                              void* d_out, int out_size, void* d_ws, size_t ws_size,
                              hipStream_t stream)
{
    const float* coord  = (const float*)d_in[0];   // [N, 2]
    const float* params = (const float*)d_in[1];   // [1, C, H, W]
    float* out = (float*)d_out;                    // [N, C]

    const size_t needed = (size_t)C * H * W * sizeof(float);   // 128 MiB

    if (ws_size >= needed) {
        float* tp = (float*)d_ws;   // [H, W, C]
        dim3 tgrid(W / 64, H);
        transpose_chw_hwc<<<tgrid, 256, 0, stream>>>(params, tp);

        const int total = N_POINTS * 8;            // 8 lanes per point
        const int blocks = (total + 255) / 256;
        sample_hwc<<<blocks, 256, 0, stream>>>(coord, tp, out);
    } else {
        const int total = N_POINTS * 32;           // 32 lanes per point
        const int blocks = (total + 255) / 256;
        sample_chw<<<blocks, 256, 0, stream>>>(coord, params, out);
    }
}